// Round 18
// baseline (161.504 us; speedup 1.0000x reference)
//
#include <hip/hip_runtime.h>
#include <cstdint>
#include <cstddef>

#define NEG_SLOPE 0.2f

typedef __bf16 bf16x8 __attribute__((ext_vector_type(8)));
typedef float f32x4 __attribute__((ext_vector_type(4)));

static __device__ __forceinline__ unsigned short f2bf(float f) {
  unsigned int u = __float_as_uint(f);
  unsigned int r = (u + 0x7FFFu + ((u >> 16) & 1u)) >> 16;
  return (unsigned short)r;
}
static __device__ __forceinline__ float bf2f(unsigned short u) {
  return __uint_as_float(((unsigned int)u) << 16);
}
static __device__ __forceinline__ float pklo(unsigned int x) {
  return __uint_as_float(x << 16);
}
static __device__ __forceinline__ float pkhi(unsigned int x) {
  return __uint_as_float(x & 0xffff0000u);
}

// ---------------- CSR scan ----------------
__global__ __launch_bounds__(256) void k_scan_local(const int* __restrict__ deg,
                                                    int* __restrict__ lex,
                                                    int* __restrict__ bsum, int n) {
  __shared__ int ts[256];
  const int t = threadIdx.x;
  const int base = blockIdx.x * 1024 + t * 4;
  int4 d = {0, 0, 0, 0};
  if (base + 3 < n) d = *reinterpret_cast<const int4*>(&deg[base]);
  else {
    if (base + 0 < n) d.x = deg[base + 0];
    if (base + 1 < n) d.y = deg[base + 1];
    if (base + 2 < n) d.z = deg[base + 2];
  }
  int s = d.x + d.y + d.z + d.w;
  ts[t] = s;
  __syncthreads();
  for (int off = 1; off < 256; off <<= 1) {
    int y = (t >= off) ? ts[t - off] : 0;
    __syncthreads();
    ts[t] += y;
    __syncthreads();
  }
  int pre = ts[t] - s;
  int4 o;
  o.x = pre; o.y = pre + d.x; o.z = pre + d.x + d.y; o.w = pre + d.x + d.y + d.z;
  if (base + 3 < n) *reinterpret_cast<int4*>(&lex[base]) = o;
  else {
    if (base + 0 < n) lex[base + 0] = o.x;
    if (base + 1 < n) lex[base + 1] = o.y;
    if (base + 2 < n) lex[base + 2] = o.z;
  }
  if (t == 255) bsum[blockIdx.x] = ts[255];
}

// scan_add with embedded (redundant per-block) bsum exclusive scan.
__global__ __launch_bounds__(256) void k_scan_add(
    const int* __restrict__ lex, const int* __restrict__ bsum,
    int* __restrict__ rowptr, int n, int nb, int E) {
  __shared__ int ts[256];
  const int t = threadIdx.x;
  int v = (t < nb) ? bsum[t] : 0;
  ts[t] = v;
  __syncthreads();
  for (int off = 1; off < 256; off <<= 1) {
    int y = (t >= off) ? ts[t - off] : 0;
    __syncthreads();
    ts[t] += y;
    __syncthreads();
  }
  int excl = ts[t] - v;
  __syncthreads();
  ts[t] = excl;
  __syncthreads();
  int i = blockIdx.x * 256 + t;
  if (i < n) rowptr[i] = lex[i] + ts[i >> 10];
  if (i == n) rowptr[n] = E;
}

// ---------------- k_init: weight pack ∪ degree count + edge rank (8/thread) --
static __device__ __forceinline__ unsigned short pack_wt_elem(
    const float* __restrict__ Wl, const float* __restrict__ Ws,
    const float* __restrict__ Wd, const float* __restrict__ as_,
    const float* __restrict__ ad_, int t) {
  int j = t >> 7, k = t & 127;
  float val;
  if (j < 128) val = Wl[k * 128 + j];
  else if (j < 256) val = Ws[k * 128 + (j - 128)];
  else {
    int jj = j - 256;
    int h = jj & 7;
    const float* W = (jj < 8) ? Ws : Wd;
    const float* a = (jj < 8) ? as_ : ad_;
    float s = 0.f;
#pragma unroll
    for (int c = 0; c < 16; ++c) s += W[k * 128 + h * 16 + c] * a[h * 16 + c];
    val = s;
  }
  return f2bf(val);
}

__global__ void k_init(
    const float* __restrict__ Wl0, const float* __restrict__ Ws0, const float* __restrict__ Wd0,
    const float* __restrict__ as0, const float* __restrict__ ad0,
    const float* __restrict__ Wl1, const float* __restrict__ Ws1, const float* __restrict__ Wd1,
    const float* __restrict__ as1, const float* __restrict__ ad1,
    const float* __restrict__ Wo,
    unsigned short* __restrict__ wt0, unsigned short* __restrict__ wt1,
    unsigned short* __restrict__ wot,
    const int* __restrict__ ei, int* __restrict__ deg,
    unsigned short* __restrict__ rank, int E, int packBlocks) {
  const int SZ = 272 * 128;
  if ((int)blockIdx.x < packBlocks) {
    int t = blockIdx.x * 256 + threadIdx.x;
    if (t < SZ) {
      wt0[t] = pack_wt_elem(Wl0, Ws0, Wd0, as0, ad0, t);
    } else if (t < 2 * SZ) {
      wt1[t - SZ] = pack_wt_elem(Wl1, Ws1, Wd1, as1, ad1, t - SZ);
    } else if (t < 2 * SZ + 64 * 128) {
      int u = t - 2 * SZ;
      int nn = u >> 7, k = u & 127;
      wot[u] = f2bf(Wo[k * 64 + nn]);
    }
  } else {
    // 8 edges per thread: 2x int4 dst loads, 8 independent atomics in flight
    int e = ((blockIdx.x - packBlocks) * 256 + threadIdx.x) * 8;
    if (e + 7 < E) {
      int4 dA = *reinterpret_cast<const int4*>(&ei[E + e]);
      int4 dB = *reinterpret_cast<const int4*>(&ei[E + e + 4]);
      ushort4 rA, rB;
      rA.x = (unsigned short)atomicAdd(&deg[dA.x], 1);
      rA.y = (unsigned short)atomicAdd(&deg[dA.y], 1);
      rA.z = (unsigned short)atomicAdd(&deg[dA.z], 1);
      rA.w = (unsigned short)atomicAdd(&deg[dA.w], 1);
      rB.x = (unsigned short)atomicAdd(&deg[dB.x], 1);
      rB.y = (unsigned short)atomicAdd(&deg[dB.y], 1);
      rB.z = (unsigned short)atomicAdd(&deg[dB.z], 1);
      rB.w = (unsigned short)atomicAdd(&deg[dB.w], 1);
      *reinterpret_cast<ushort4*>(&rank[e]) = rA;
      *reinterpret_cast<ushort4*>(&rank[e + 4]) = rB;
    } else {
      for (int q = 0; q < 8 && e + q < E; ++q)
        rank[e + q] = (unsigned short)atomicAdd(&deg[ei[E + e + q]], 1);
    }
  }
}

// ---- shared GEMM body: one 32-row tile, B-frags already in registers ----
template <typename TIN, bool NT>
static __device__ __forceinline__ void gemm_tile_body(
    const TIN* __restrict__ X, const bf16x8 bfr[4][4], const bf16x8 bfr4[4],
    const float* __restrict__ bl, const float* __restrict__ bc,
    unsigned int* __restrict__ ylin_pk, unsigned short* __restrict__ xsb,
    unsigned short* __restrict__ asd_s, unsigned short* __restrict__ asd_d,
    int n, int row0, unsigned short (*xa)[136],
    int tid, int wave, int lane, int lr, int lg, int f0, bool w3) {
  if constexpr (sizeof(TIN) == 4) {
#pragma unroll
    for (int ii = 0; ii < 4; ++ii) {
      int c = tid + ii * 256;
      int r = c >> 5, kq = c & 31;
      f32x4 v = (f32x4){0.f, 0.f, 0.f, 0.f};
      if (row0 + r < n) {
        const f32x4* src = &reinterpret_cast<const f32x4*>(X)[(size_t)(row0 + r) * 32 + kq];
        v = NT ? __builtin_nontemporal_load(src) : *src;
      }
      ushort4 o;
      o.x = f2bf(v.x); o.y = f2bf(v.y); o.z = f2bf(v.z); o.w = f2bf(v.w);
      *reinterpret_cast<ushort4*>(&xa[r][kq * 4]) = o;
    }
  } else {
#pragma unroll
    for (int ii = 0; ii < 2; ++ii) {
      int c = tid + ii * 256;
      int r = c >> 4, ko = c & 15;
      uint4 v = {0u, 0u, 0u, 0u};
      if (row0 + r < n)
        v = reinterpret_cast<const uint4*>(X)[(size_t)(row0 + r) * 16 + ko];
      *reinterpret_cast<uint4*>(&xa[r][ko * 8]) = v;
    }
  }
  __syncthreads();

  f32x4 acc[2][4];
  f32x4 acc4[2];
#pragma unroll
  for (int g = 0; g < 2; ++g) {
    acc4[g] = (f32x4){0.f, 0.f, 0.f, 0.f};
#pragma unroll
    for (int ff = 0; ff < 4; ++ff) acc[g][ff] = (f32x4){0.f, 0.f, 0.f, 0.f};
  }

#pragma unroll
  for (int s = 0; s < 4; ++s) {
    bf16x8 a0 = *reinterpret_cast<const bf16x8*>(&xa[lr][s * 32 + lg * 8]);
    bf16x8 a1 = *reinterpret_cast<const bf16x8*>(&xa[16 + lr][s * 32 + lg * 8]);
#pragma unroll
    for (int ff = 0; ff < 4; ++ff) {
      acc[0][ff] = __builtin_amdgcn_mfma_f32_16x16x32_bf16(a0, bfr[ff][s], acc[0][ff], 0, 0, 0);
      acc[1][ff] = __builtin_amdgcn_mfma_f32_16x16x32_bf16(a1, bfr[ff][s], acc[1][ff], 0, 0, 0);
    }
    if (w3) {
      acc4[0] = __builtin_amdgcn_mfma_f32_16x16x32_bf16(a0, bfr4[s], acc4[0], 0, 0, 0);
      acc4[1] = __builtin_amdgcn_mfma_f32_16x16x32_bf16(a1, bfr4[s], acc4[1], 0, 0, 0);
    }
  }

  if (f0 < 8) {
#pragma unroll
    for (int g = 0; g < 2; ++g)
#pragma unroll
      for (int ff = 0; ff < 4; ++ff) {
        int j = (f0 + ff) * 16 + lr;
        float blc = bl[j] + bc[j];
#pragma unroll
        for (int r = 0; r < 4; ++r) {
          int row = row0 + g * 16 + lg * 4 + r;
          float vb = acc[g][ff][r] + blc;
          float v2 = __shfl(vb, lane ^ 1);
          if (row < n && (lr & 1) == 0)
            ylin_pk[(size_t)row * 64 + (j >> 1)] =
                (unsigned int)f2bf(vb) | ((unsigned int)f2bf(v2) << 16);
        }
      }
  } else {
#pragma unroll
    for (int g = 0; g < 2; ++g)
#pragma unroll
      for (int ff = 0; ff < 4; ++ff) {
        int j = (f0 - 8 + ff) * 16 + lr;
#pragma unroll
        for (int r = 0; r < 4; ++r) {
          int row = row0 + g * 16 + lg * 4 + r;
          if (row < n) xsb[(size_t)row * 128 + j] = f2bf(acc[g][ff][r]);
        }
      }
    if (w3) {
#pragma unroll
      for (int g = 0; g < 2; ++g)
#pragma unroll
        for (int r = 0; r < 4; ++r) {
          int row = row0 + g * 16 + lg * 4 + r;
          if (row < n) {
            unsigned short v = f2bf(acc4[g][r]);
            if (lr < 8) asd_s[(size_t)row * 8 + lr] = v;
            else        asd_d[(size_t)row * 8 + (lr - 8)] = v;
          }
        }
    }
  }
}

// ---------------- k_gemm0_scatter: layer-0 GEMM (2 tiles/block) ∪ scatter ----
__global__ __launch_bounds__(256, 3) void k_gemm0_scatter(
    const float* __restrict__ X, const unsigned short* __restrict__ wt,
    const float* __restrict__ bl, const float* __restrict__ bc,
    unsigned int* __restrict__ ylin_pk, unsigned short* __restrict__ xsb,
    unsigned short* __restrict__ asd_s, unsigned short* __restrict__ asd_d,
    int n, int ntiles, int gemmBlocks,
    const int* __restrict__ ei, const int* __restrict__ rowptr,
    const unsigned short* __restrict__ rank,
    unsigned short* __restrict__ col, int E, int total) {
  __shared__ __align__(16) unsigned short xa[32][136];
  const int i = blockIdx.x;
  const int before = (int)(((long long)i * gemmBlocks) / total);
  const int after  = (int)(((long long)(i + 1) * gemmBlocks) / total);

  if (after == before) {     // ---- scatter block (no atomics, 8 edges/thread) ----
    int e = ((i - after) * 256 + threadIdx.x) * 8;
    if (e + 7 < E) {
      int4 sA = *reinterpret_cast<const int4*>(&ei[e]);
      int4 sB = *reinterpret_cast<const int4*>(&ei[e + 4]);
      int4 dA = *reinterpret_cast<const int4*>(&ei[E + e]);
      int4 dB = *reinterpret_cast<const int4*>(&ei[E + e + 4]);
      ushort4 rA = *reinterpret_cast<const ushort4*>(&rank[e]);
      ushort4 rB = *reinterpret_cast<const ushort4*>(&rank[e + 4]);
      int p0 = rowptr[dA.x] + (int)rA.x;
      int p1 = rowptr[dA.y] + (int)rA.y;
      int p2 = rowptr[dA.z] + (int)rA.z;
      int p3 = rowptr[dA.w] + (int)rA.w;
      int p4 = rowptr[dB.x] + (int)rB.x;
      int p5 = rowptr[dB.y] + (int)rB.y;
      int p6 = rowptr[dB.z] + (int)rB.z;
      int p7 = rowptr[dB.w] + (int)rB.w;
      col[p0] = (unsigned short)sA.x;
      col[p1] = (unsigned short)sA.y;
      col[p2] = (unsigned short)sA.z;
      col[p3] = (unsigned short)sA.w;
      col[p4] = (unsigned short)sB.x;
      col[p5] = (unsigned short)sB.y;
      col[p6] = (unsigned short)sB.z;
      col[p7] = (unsigned short)sB.w;
    } else {
      for (int q = 0; q < 8 && e + q < E; ++q) {
        int d = ei[E + e + q];
        col[rowptr[d] + (int)rank[e + q]] = (unsigned short)ei[e + q];
      }
    }
    return;
  }

  // ---- gemm block: tiles 2*before and 2*before+1, B-frags reused ----
  const int tid = threadIdx.x;
  const int wave = tid >> 6, lane = tid & 63;
  const int lr = lane & 15, lg = lane >> 4;
  const int f0 = wave * 4;
  const bool w3 = (wave == 3);

  bf16x8 bfr[4][4];
#pragma unroll
  for (int ff = 0; ff < 4; ++ff)
#pragma unroll
    for (int s = 0; s < 4; ++s)
      bfr[ff][s] = *reinterpret_cast<const bf16x8*>(
          &wt[(size_t)((f0 + ff) * 16 + lr) * 128 + s * 32 + lg * 8]);
  bf16x8 bfr4[4];
  if (w3) {
#pragma unroll
    for (int s = 0; s < 4; ++s)
      bfr4[s] = *reinterpret_cast<const bf16x8*>(
          &wt[(size_t)(256 + lr) * 128 + s * 32 + lg * 8]);
  }

#pragma unroll
  for (int t2 = 0; t2 < 2; ++t2) {
    int tile = before * 2 + t2;
    if (tile >= ntiles) break;
    if (t2) __syncthreads();
    gemm_tile_body<float, true>(X, bfr, bfr4, bl, bc, ylin_pk, xsb, asd_s, asd_d,
                                n, tile * 32, xa, tid, wave, lane, lr, lg, f0, w3);
  }
}

// ---------------- layer-1 fused MFMA GEMM (bf16 input, 2 tiles/block) --------
__global__ __launch_bounds__(256, 3) void k_gemm_fused1(
    const unsigned short* __restrict__ X, const unsigned short* __restrict__ wt,
    const float* __restrict__ bl, const float* __restrict__ bc,
    unsigned int* __restrict__ ylin_pk, unsigned short* __restrict__ xsb,
    unsigned short* __restrict__ asd_s, unsigned short* __restrict__ asd_d,
    int n, int ntiles) {
  __shared__ __align__(16) unsigned short xa[32][136];
  const int tid = threadIdx.x;
  const int wave = tid >> 6, lane = tid & 63;
  const int lr = lane & 15, lg = lane >> 4;
  const int f0 = wave * 4;
  const bool w3 = (wave == 3);

  bf16x8 bfr[4][4];
#pragma unroll
  for (int ff = 0; ff < 4; ++ff)
#pragma unroll
    for (int s = 0; s < 4; ++s)
      bfr[ff][s] = *reinterpret_cast<const bf16x8*>(
          &wt[(size_t)((f0 + ff) * 16 + lr) * 128 + s * 32 + lg * 8]);
  bf16x8 bfr4[4];
  if (w3) {
#pragma unroll
    for (int s = 0; s < 4; ++s)
      bfr4[s] = *reinterpret_cast<const bf16x8*>(
          &wt[(size_t)(256 + lr) * 128 + s * 32 + lg * 8]);
  }

#pragma unroll
  for (int t2 = 0; t2 < 2; ++t2) {
    int tile = blockIdx.x * 2 + t2;
    if (tile >= ntiles) break;
    if (t2) __syncthreads();
    gemm_tile_body<unsigned short, false>(X, bfr, bfr4, bl, bc, ylin_pk, xsb,
                                          asd_s, asd_d, n, tile * 32, xa,
                                          tid, wave, lane, lr, lg, f0, w3);
  }
}

// ---------------- final GEMM: out[N,64] = h@W_out + b (2 tiles/block) --------
__global__ __launch_bounds__(256, 3) void k_gemm_out(
    const unsigned short* __restrict__ X, const unsigned short* __restrict__ wot,
    const float* __restrict__ bias, float* __restrict__ out, int n, int ntiles) {
  __shared__ __align__(16) unsigned short xa[32][136];
  const int tid = threadIdx.x;
  const int wave = tid >> 6, lane = tid & 63;
  const int lr = lane & 15, lg = lane >> 4;

  bf16x8 bo[4];
#pragma unroll
  for (int s = 0; s < 4; ++s)
    bo[s] = *reinterpret_cast<const bf16x8*>(
        &wot[(size_t)(wave * 16 + lr) * 128 + s * 32 + lg * 8]);
  float bv = bias[wave * 16 + lr];

#pragma unroll
  for (int t2 = 0; t2 < 2; ++t2) {
    int tile = blockIdx.x * 2 + t2;
    if (tile >= ntiles) break;
    if (t2) __syncthreads();
    const int row0 = tile * 32;
#pragma unroll
    for (int i = 0; i < 2; ++i) {
      int c = tid + i * 256;
      int r = c >> 4, ko = c & 15;
      uint4 v = {0u, 0u, 0u, 0u};
      if (row0 + r < n)
        v = reinterpret_cast<const uint4*>(X)[(size_t)(row0 + r) * 16 + ko];
      *reinterpret_cast<uint4*>(&xa[r][ko * 8]) = v;
    }
    __syncthreads();

    f32x4 acc[2];
    acc[0] = (f32x4){0.f, 0.f, 0.f, 0.f};
    acc[1] = (f32x4){0.f, 0.f, 0.f, 0.f};
#pragma unroll
    for (int s = 0; s < 4; ++s) {
      bf16x8 a0 = *reinterpret_cast<const bf16x8*>(&xa[lr][s * 32 + lg * 8]);
      bf16x8 a1 = *reinterpret_cast<const bf16x8*>(&xa[16 + lr][s * 32 + lg * 8]);
      acc[0] = __builtin_amdgcn_mfma_f32_16x16x32_bf16(a0, bo[s], acc[0], 0, 0, 0);
      acc[1] = __builtin_amdgcn_mfma_f32_16x16x32_bf16(a1, bo[s], acc[1], 0, 0, 0);
    }
#pragma unroll
    for (int g = 0; g < 2; ++g)
#pragma unroll
      for (int r = 0; r < 4; ++r) {
        int row = row0 + g * 16 + lg * 4 + r;
        if (row < n) out[(size_t)row * 64 + wave * 16 + lr] = acc[g][r] + bv;
      }
  }
}

// ---------------- fused segment softmax + aggregation + node update ----------
// One wave per dst node. 16-edge software-pipelined chunks with next-chunk col
// prefetch; branchless padding.
__global__ __launch_bounds__(256) void k_aggregate(
    const unsigned int* __restrict__ ylin_pk, const unsigned int* __restrict__ xsp,
    const unsigned short* __restrict__ asd_s, const unsigned short* __restrict__ asd_d,
    const int* __restrict__ rowptr, const unsigned short* __restrict__ col,
    unsigned int* __restrict__ hout_pk, int n) {
  int node = (blockIdx.x * blockDim.x + threadIdx.x) >> 6;
  if (node >= n) return;
  const int lane = threadIdx.x & 63;
  const int el = lane >> 3;
  const int hh = lane & 7;
  const int hb4 = (lane >> 3) << 2;
  const int beg = rowptr[node], end = rowptr[node + 1];

  const float ad_hh = bf2f(asd_d[(size_t)node * 8 + hh]);
  unsigned int y = __builtin_nontemporal_load(&ylin_pk[(size_t)node * 64 + lane]);

  float dsum = 0.f, acc0 = 0.f, acc1 = 0.f;
  int ebase = beg;
  // prefetch first chunk's col
  int eA0 = beg + el;
  int srcA = (eA0 < end) ? (int)col[eA0] : 0;
  for (; ebase + 8 < end; ebase += 16) {
    int eB = ebase + 8 + el;
    bool vB = eB < end;
    int esB = vB ? eB : (end - 1);
    int srcB = (int)col[esB];
    // prefetch next iteration's chunk-A col
    int eN = ebase + 16 + el;
    int srcN = (eN < end) ? (int)col[eN] : 0;
    float svA = bf2f(asd_s[(size_t)srcA * 8 + hh]) + ad_hh;
    float svB = bf2f(asd_s[(size_t)srcB * 8 + hh]) + ad_hh;
    svA = fmaxf(svA, NEG_SLOPE * svA);
    svB = fmaxf(svB, NEG_SLOPE * svB);
    float peA = __expf(svA);
    float peB = vB ? __expf(svB) : 0.f;
#pragma unroll
    for (int q = 0; q < 8; ++q) {
      float pq = __uint_as_float(__builtin_amdgcn_ds_bpermute(
          q * 32 + hb4, __float_as_uint(peA)));
      int sq = __builtin_amdgcn_readlane(srcA, q * 8);
      unsigned int xv = xsp[(size_t)sq * 64 + lane];
      dsum += pq;
      acc0 += pq * pklo(xv);
      acc1 += pq * pkhi(xv);
    }
#pragma unroll
    for (int q = 0; q < 8; ++q) {
      float pq = __uint_as_float(__builtin_amdgcn_ds_bpermute(
          q * 32 + hb4, __float_as_uint(peB)));
      int sq = __builtin_amdgcn_readlane(srcB, q * 8);
      unsigned int xv = xsp[(size_t)sq * 64 + lane];
      dsum += pq;
      acc0 += pq * pklo(xv);
      acc1 += pq * pkhi(xv);
    }
    srcA = srcN;
  }
  for (; ebase < end; ebase += 8) {
    int e1 = ebase + el;
    bool valid = e1 < end;
    int esafe = valid ? e1 : (end - 1);
    int srcp = (int)col[esafe];
    float sv = bf2f(asd_s[(size_t)srcp * 8 + hh]) + ad_hh;
    sv = fmaxf(sv, NEG_SLOPE * sv);
    float pe = valid ? __expf(sv) : 0.f;
#pragma unroll
    for (int q = 0; q < 8; ++q) {
      float pq = __uint_as_float(__builtin_amdgcn_ds_bpermute(
          q * 32 + hb4, __float_as_uint(pe)));
      int sq = __builtin_amdgcn_readlane(srcp, q * 8);
      unsigned int xv = xsp[(size_t)sq * 64 + lane];
      dsum += pq;
      acc0 += pq * pklo(xv);
      acc1 += pq * pkhi(xv);
    }
  }
  float inv = 1.f / (dsum + 1e-16f);
  float l0 = pklo(y) + acc0 * inv;
  float l1 = pkhi(y) + acc1 * inv;
  l0 = l0 > 0.f ? l0 : __expf(l0) - 1.f;
  l1 = l1 > 0.f ? l1 : __expf(l1) - 1.f;
  hout_pk[(size_t)node * 64 + lane] =
      (unsigned int)f2bf(l0) | ((unsigned int)f2bf(l1) << 16);
}

// ---------------- launch ----------------
extern "C" void kernel_launch(void* const* d_in, const int* in_sizes, int n_in,
                              void* d_out, int out_size, void* d_ws, size_t ws_size,
                              hipStream_t stream) {
  const float* x      = (const float*)d_in[0];
  const int*   ei     = (const int*)d_in[1];
  const float* W_lin0 = (const float*)d_in[2];
  const float* b_lin0 = (const float*)d_in[3];
  const float* W_src0 = (const float*)d_in[4];
  const float* W_dst0 = (const float*)d_in[5];
  const float* att_s0 = (const float*)d_in[6];
  const float* att_d0 = (const float*)d_in[7];
  const float* b_cnv0 = (const float*)d_in[8];
  const float* W_lin1 = (const float*)d_in[9];
  const float* b_lin1 = (const float*)d_in[10];
  const float* W_src1 = (const float*)d_in[11];
  const float* W_dst1 = (const float*)d_in[12];
  const float* att_s1 = (const float*)d_in[13];
  const float* att_d1 = (const float*)d_in[14];
  const float* b_cnv1 = (const float*)d_in[15];
  const float* W_out  = (const float*)d_in[16];
  const float* b_out  = (const float*)d_in[17];
  float* out = (float*)d_out;

  const int N = in_sizes[0] / 128;
  const int E = in_sizes[1] / 2;
  const int NB = (N + 1023) / 1024;
  const int MB32 = (N + 31) / 32;
  const int MBH = (MB32 + 1) / 2;
  const int SB8 = (E + 2047) / 2048;   // 8 edges/thread blocks
  const int PACKB = (2 * 272 * 128 + 64 * 128 + 255) / 256;

  char* p = (char*)d_ws;
  unsigned int* ylin    = (unsigned int*)p;   p += (size_t)N * 64 * 4;
  unsigned short* xsb   = (unsigned short*)p; p += (size_t)N * 128 * 2;
  unsigned short* hb    = (unsigned short*)p; p += (size_t)N * 128 * 2;
  unsigned short* asd_s = (unsigned short*)p; p += (size_t)N * 8 * 2;
  unsigned short* asd_d = (unsigned short*)p; p += (size_t)N * 8 * 2;
  unsigned short* wt0   = (unsigned short*)p; p += (size_t)272 * 128 * 2;
  unsigned short* wt1   = (unsigned short*)p; p += (size_t)272 * 128 * 2;
  unsigned short* wot   = (unsigned short*)p; p += (size_t)64 * 128 * 2;
  int* rowptr = (int*)p;                      p += (size_t)(N + 4) * 4;
  int* deg    = (int*)p;                      p += (size_t)N * 4;
  int* lex    = (int*)p;                      p += (size_t)N * 4;
  int* bsum   = (int*)p;                      p += (size_t)256 * 4;
  unsigned short* col  = (unsigned short*)p;  p += (size_t)E * 2;
  unsigned short* rank = (unsigned short*)p;  p += (size_t)E * 2;

  dim3 b256(256);

  (void)hipMemsetAsync(deg, 0, (size_t)N * 4, stream);
  k_init<<<PACKB + SB8, b256, 0, stream>>>(
      W_lin0, W_src0, W_dst0, att_s0, att_d0,
      W_lin1, W_src1, W_dst1, att_s1, att_d1,
      W_out, wt0, wt1, wot, ei, deg, rank, E, PACKB);
  k_scan_local<<<NB, b256, 0, stream>>>(deg, lex, bsum, N);
  k_scan_add<<<(N + 256) / 256, b256, 0, stream>>>(lex, bsum, rowptr, N, NB, E);

  // layer-0 GEMM (2 tiles/block) ∪ atomic-free CSR scatter, interleaved
  k_gemm0_scatter<<<MBH + SB8, b256, 0, stream>>>(
      x, wt0, b_lin0, b_cnv0, ylin, xsb, asd_s, asd_d, N, MB32, MBH,
      ei, rowptr, rank, col, E, MBH + SB8);

  k_aggregate<<<(N + 3) / 4, b256, 0, stream>>>(
      ylin, (const unsigned int*)xsb, asd_s, asd_d, rowptr, col,
      (unsigned int*)hb, N);
  k_gemm_fused1<<<MBH, b256, 0, stream>>>(hb, wt1, b_lin1, b_cnv1,
                                          ylin, xsb, asd_s, asd_d, N, MB32);
  k_aggregate<<<(N + 3) / 4, b256, 0, stream>>>(
      ylin, (const unsigned int*)xsb, asd_s, asd_d, rowptr, col,
      (unsigned int*)hb, N);
  k_gemm_out<<<MBH, b256, 0, stream>>>(hb, wot, b_out, out, N, MB32);
}

// Round 19
// 154.353 us; speedup vs baseline: 1.0463x; 1.0463x over previous
//
#include <hip/hip_runtime.h>
#include <cstdint>
#include <cstddef>

#define NEG_SLOPE 0.2f

typedef __bf16 bf16x8 __attribute__((ext_vector_type(8)));
typedef float f32x4 __attribute__((ext_vector_type(4)));

static __device__ __forceinline__ unsigned short f2bf(float f) {
  unsigned int u = __float_as_uint(f);
  unsigned int r = (u + 0x7FFFu + ((u >> 16) & 1u)) >> 16;
  return (unsigned short)r;
}
static __device__ __forceinline__ float bf2f(unsigned short u) {
  return __uint_as_float(((unsigned int)u) << 16);
}
static __device__ __forceinline__ float pklo(unsigned int x) {
  return __uint_as_float(x << 16);
}
static __device__ __forceinline__ float pkhi(unsigned int x) {
  return __uint_as_float(x & 0xffff0000u);
}

// ---------------- CSR scan ----------------
__global__ __launch_bounds__(256) void k_scan_local(const int* __restrict__ deg,
                                                    int* __restrict__ lex,
                                                    int* __restrict__ bsum, int n) {
  __shared__ int ts[256];
  const int t = threadIdx.x;
  const int base = blockIdx.x * 1024 + t * 4;
  int4 d = {0, 0, 0, 0};
  if (base + 3 < n) d = *reinterpret_cast<const int4*>(&deg[base]);
  else {
    if (base + 0 < n) d.x = deg[base + 0];
    if (base + 1 < n) d.y = deg[base + 1];
    if (base + 2 < n) d.z = deg[base + 2];
  }
  int s = d.x + d.y + d.z + d.w;
  ts[t] = s;
  __syncthreads();
  for (int off = 1; off < 256; off <<= 1) {
    int y = (t >= off) ? ts[t - off] : 0;
    __syncthreads();
    ts[t] += y;
    __syncthreads();
  }
  int pre = ts[t] - s;
  int4 o;
  o.x = pre; o.y = pre + d.x; o.z = pre + d.x + d.y; o.w = pre + d.x + d.y + d.z;
  if (base + 3 < n) *reinterpret_cast<int4*>(&lex[base]) = o;
  else {
    if (base + 0 < n) lex[base + 0] = o.x;
    if (base + 1 < n) lex[base + 1] = o.y;
    if (base + 2 < n) lex[base + 2] = o.z;
  }
  if (t == 255) bsum[blockIdx.x] = ts[255];
}

// scan_add with embedded (redundant per-block) bsum exclusive scan.
__global__ __launch_bounds__(256) void k_scan_add(
    const int* __restrict__ lex, const int* __restrict__ bsum,
    int* __restrict__ rowptr, int n, int nb, int E) {
  __shared__ int ts[256];
  const int t = threadIdx.x;
  int v = (t < nb) ? bsum[t] : 0;
  ts[t] = v;
  __syncthreads();
  for (int off = 1; off < 256; off <<= 1) {
    int y = (t >= off) ? ts[t - off] : 0;
    __syncthreads();
    ts[t] += y;
    __syncthreads();
  }
  int excl = ts[t] - v;
  __syncthreads();
  ts[t] = excl;
  __syncthreads();
  int i = blockIdx.x * 256 + t;
  if (i < n) rowptr[i] = lex[i] + ts[i >> 10];
  if (i == n) rowptr[n] = E;
}

// ---------------- k_init: weight pack ∪ degree count + edge rank (4/thread) --
static __device__ __forceinline__ unsigned short pack_wt_elem(
    const float* __restrict__ Wl, const float* __restrict__ Ws,
    const float* __restrict__ Wd, const float* __restrict__ as_,
    const float* __restrict__ ad_, int t) {
  int j = t >> 7, k = t & 127;
  float val;
  if (j < 128) val = Wl[k * 128 + j];
  else if (j < 256) val = Ws[k * 128 + (j - 128)];
  else {
    int jj = j - 256;
    int h = jj & 7;
    const float* W = (jj < 8) ? Ws : Wd;
    const float* a = (jj < 8) ? as_ : ad_;
    float s = 0.f;
#pragma unroll
    for (int c = 0; c < 16; ++c) s += W[k * 128 + h * 16 + c] * a[h * 16 + c];
    val = s;
  }
  return f2bf(val);
}

__global__ void k_init(
    const float* __restrict__ Wl0, const float* __restrict__ Ws0, const float* __restrict__ Wd0,
    const float* __restrict__ as0, const float* __restrict__ ad0,
    const float* __restrict__ Wl1, const float* __restrict__ Ws1, const float* __restrict__ Wd1,
    const float* __restrict__ as1, const float* __restrict__ ad1,
    const float* __restrict__ Wo,
    unsigned short* __restrict__ wt0, unsigned short* __restrict__ wt1,
    unsigned short* __restrict__ wot,
    const int* __restrict__ ei, int* __restrict__ deg,
    unsigned short* __restrict__ rank, int E, int packBlocks) {
  const int SZ = 272 * 128;
  if ((int)blockIdx.x < packBlocks) {
    int t = blockIdx.x * 256 + threadIdx.x;
    if (t < SZ) {
      wt0[t] = pack_wt_elem(Wl0, Ws0, Wd0, as0, ad0, t);
    } else if (t < 2 * SZ) {
      wt1[t - SZ] = pack_wt_elem(Wl1, Ws1, Wd1, as1, ad1, t - SZ);
    } else if (t < 2 * SZ + 64 * 128) {
      int u = t - 2 * SZ;
      int nn = u >> 7, k = u & 127;
      wot[u] = f2bf(Wo[k * 64 + nn]);
    }
  } else {
    int e = ((blockIdx.x - packBlocks) * 256 + threadIdx.x) * 4;
    if (e + 3 < E) {
      int4 d4 = *reinterpret_cast<const int4*>(&ei[E + e]);
      ushort4 r4;
      r4.x = (unsigned short)atomicAdd(&deg[d4.x], 1);
      r4.y = (unsigned short)atomicAdd(&deg[d4.y], 1);
      r4.z = (unsigned short)atomicAdd(&deg[d4.z], 1);
      r4.w = (unsigned short)atomicAdd(&deg[d4.w], 1);
      *reinterpret_cast<ushort4*>(&rank[e]) = r4;
    } else {
      for (int q = 0; q < 4 && e + q < E; ++q)
        rank[e + q] = (unsigned short)atomicAdd(&deg[ei[E + e + q]], 1);
    }
  }
}

// ---- shared GEMM body: one 32-row tile, B-frags already in registers ----
template <typename TIN>
static __device__ __forceinline__ void gemm_tile_body(
    const TIN* __restrict__ X, const bf16x8 bfr[4][4], const bf16x8 bfr4[4],
    const float* __restrict__ bl, const float* __restrict__ bc,
    unsigned int* __restrict__ ylin_pk, unsigned short* __restrict__ xsb,
    unsigned short* __restrict__ asd_s, unsigned short* __restrict__ asd_d,
    int n, int row0, unsigned short (*xa)[136],
    int tid, int wave, int lane, int lr, int lg, int f0, bool w3) {
  if constexpr (sizeof(TIN) == 4) {
#pragma unroll
    for (int ii = 0; ii < 4; ++ii) {
      int c = tid + ii * 256;
      int r = c >> 5, kq = c & 31;
      float4 v = make_float4(0.f, 0.f, 0.f, 0.f);
      if (row0 + r < n)
        v = reinterpret_cast<const float4*>(X)[(size_t)(row0 + r) * 32 + kq];
      ushort4 o;
      o.x = f2bf(v.x); o.y = f2bf(v.y); o.z = f2bf(v.z); o.w = f2bf(v.w);
      *reinterpret_cast<ushort4*>(&xa[r][kq * 4]) = o;
    }
  } else {
#pragma unroll
    for (int ii = 0; ii < 2; ++ii) {
      int c = tid + ii * 256;
      int r = c >> 4, ko = c & 15;
      uint4 v = {0u, 0u, 0u, 0u};
      if (row0 + r < n)
        v = reinterpret_cast<const uint4*>(X)[(size_t)(row0 + r) * 16 + ko];
      *reinterpret_cast<uint4*>(&xa[r][ko * 8]) = v;
    }
  }
  __syncthreads();

  f32x4 acc[2][4];
  f32x4 acc4[2];
#pragma unroll
  for (int g = 0; g < 2; ++g) {
    acc4[g] = (f32x4){0.f, 0.f, 0.f, 0.f};
#pragma unroll
    for (int ff = 0; ff < 4; ++ff) acc[g][ff] = (f32x4){0.f, 0.f, 0.f, 0.f};
  }

#pragma unroll
  for (int s = 0; s < 4; ++s) {
    bf16x8 a0 = *reinterpret_cast<const bf16x8*>(&xa[lr][s * 32 + lg * 8]);
    bf16x8 a1 = *reinterpret_cast<const bf16x8*>(&xa[16 + lr][s * 32 + lg * 8]);
#pragma unroll
    for (int ff = 0; ff < 4; ++ff) {
      acc[0][ff] = __builtin_amdgcn_mfma_f32_16x16x32_bf16(a0, bfr[ff][s], acc[0][ff], 0, 0, 0);
      acc[1][ff] = __builtin_amdgcn_mfma_f32_16x16x32_bf16(a1, bfr[ff][s], acc[1][ff], 0, 0, 0);
    }
    if (w3) {
      acc4[0] = __builtin_amdgcn_mfma_f32_16x16x32_bf16(a0, bfr4[s], acc4[0], 0, 0, 0);
      acc4[1] = __builtin_amdgcn_mfma_f32_16x16x32_bf16(a1, bfr4[s], acc4[1], 0, 0, 0);
    }
  }

  if (f0 < 8) {
#pragma unroll
    for (int g = 0; g < 2; ++g)
#pragma unroll
      for (int ff = 0; ff < 4; ++ff) {
        int j = (f0 + ff) * 16 + lr;
        float blc = bl[j] + bc[j];
#pragma unroll
        for (int r = 0; r < 4; ++r) {
          int row = row0 + g * 16 + lg * 4 + r;
          float vb = acc[g][ff][r] + blc;
          float v2 = __shfl(vb, lane ^ 1);
          if (row < n && (lr & 1) == 0)
            ylin_pk[(size_t)row * 64 + (j >> 1)] =
                (unsigned int)f2bf(vb) | ((unsigned int)f2bf(v2) << 16);
        }
      }
  } else {
#pragma unroll
    for (int g = 0; g < 2; ++g)
#pragma unroll
      for (int ff = 0; ff < 4; ++ff) {
        int j = (f0 - 8 + ff) * 16 + lr;
#pragma unroll
        for (int r = 0; r < 4; ++r) {
          int row = row0 + g * 16 + lg * 4 + r;
          if (row < n) xsb[(size_t)row * 128 + j] = f2bf(acc[g][ff][r]);
        }
      }
    if (w3) {
#pragma unroll
      for (int g = 0; g < 2; ++g)
#pragma unroll
        for (int r = 0; r < 4; ++r) {
          int row = row0 + g * 16 + lg * 4 + r;
          if (row < n) {
            unsigned short v = f2bf(acc4[g][r]);
            if (lr < 8) asd_s[(size_t)row * 8 + lr] = v;
            else        asd_d[(size_t)row * 8 + (lr - 8)] = v;
          }
        }
    }
  }
}

// ---------------- k_gemm0_scatter: layer-0 GEMM (2 tiles/block) ∪ scatter ----
__global__ __launch_bounds__(256, 3) void k_gemm0_scatter(
    const float* __restrict__ X, const unsigned short* __restrict__ wt,
    const float* __restrict__ bl, const float* __restrict__ bc,
    unsigned int* __restrict__ ylin_pk, unsigned short* __restrict__ xsb,
    unsigned short* __restrict__ asd_s, unsigned short* __restrict__ asd_d,
    int n, int ntiles, int gemmBlocks,
    const int* __restrict__ ei, const int* __restrict__ rowptr,
    const unsigned short* __restrict__ rank,
    unsigned short* __restrict__ col, int E, int total) {
  __shared__ __align__(16) unsigned short xa[32][136];
  const int i = blockIdx.x;
  const int before = (int)(((long long)i * gemmBlocks) / total);
  const int after  = (int)(((long long)(i + 1) * gemmBlocks) / total);

  if (after == before) {           // ---- scatter block (no atomics, 4/thread) ----
    int e = ((i - after) * 256 + threadIdx.x) * 4;
    if (e + 3 < E) {
      int4 s4 = *reinterpret_cast<const int4*>(&ei[e]);
      int4 d4 = *reinterpret_cast<const int4*>(&ei[E + e]);
      ushort4 r4 = *reinterpret_cast<const ushort4*>(&rank[e]);
      int p0 = rowptr[d4.x] + (int)r4.x;
      int p1 = rowptr[d4.y] + (int)r4.y;
      int p2 = rowptr[d4.z] + (int)r4.z;
      int p3 = rowptr[d4.w] + (int)r4.w;
      col[p0] = (unsigned short)s4.x;
      col[p1] = (unsigned short)s4.y;
      col[p2] = (unsigned short)s4.z;
      col[p3] = (unsigned short)s4.w;
    } else {
      for (int q = 0; q < 4 && e + q < E; ++q) {
        int d = ei[E + e + q];
        col[rowptr[d] + (int)rank[e + q]] = (unsigned short)ei[e + q];
      }
    }
    return;
  }

  // ---- gemm block: tiles 2*before and 2*before+1, B-frags reused ----
  const int tid = threadIdx.x;
  const int wave = tid >> 6, lane = tid & 63;
  const int lr = lane & 15, lg = lane >> 4;
  const int f0 = wave * 4;
  const bool w3 = (wave == 3);

  bf16x8 bfr[4][4];
#pragma unroll
  for (int ff = 0; ff < 4; ++ff)
#pragma unroll
    for (int s = 0; s < 4; ++s)
      bfr[ff][s] = *reinterpret_cast<const bf16x8*>(
          &wt[(size_t)((f0 + ff) * 16 + lr) * 128 + s * 32 + lg * 8]);
  bf16x8 bfr4[4];
  if (w3) {
#pragma unroll
    for (int s = 0; s < 4; ++s)
      bfr4[s] = *reinterpret_cast<const bf16x8*>(
          &wt[(size_t)(256 + lr) * 128 + s * 32 + lg * 8]);
  }

#pragma unroll
  for (int t2 = 0; t2 < 2; ++t2) {
    int tile = before * 2 + t2;
    if (tile >= ntiles) break;
    if (t2) __syncthreads();
    gemm_tile_body<float>(X, bfr, bfr4, bl, bc, ylin_pk, xsb, asd_s, asd_d,
                          n, tile * 32, xa, tid, wave, lane, lr, lg, f0, w3);
  }
}

// ---------------- layer-1 fused MFMA GEMM (bf16 input, 2 tiles/block) --------
__global__ __launch_bounds__(256, 3) void k_gemm_fused1(
    const unsigned short* __restrict__ X, const unsigned short* __restrict__ wt,
    const float* __restrict__ bl, const float* __restrict__ bc,
    unsigned int* __restrict__ ylin_pk, unsigned short* __restrict__ xsb,
    unsigned short* __restrict__ asd_s, unsigned short* __restrict__ asd_d,
    int n, int ntiles) {
  __shared__ __align__(16) unsigned short xa[32][136];
  const int tid = threadIdx.x;
  const int wave = tid >> 6, lane = tid & 63;
  const int lr = lane & 15, lg = lane >> 4;
  const int f0 = wave * 4;
  const bool w3 = (wave == 3);

  bf16x8 bfr[4][4];
#pragma unroll
  for (int ff = 0; ff < 4; ++ff)
#pragma unroll
    for (int s = 0; s < 4; ++s)
      bfr[ff][s] = *reinterpret_cast<const bf16x8*>(
          &wt[(size_t)((f0 + ff) * 16 + lr) * 128 + s * 32 + lg * 8]);
  bf16x8 bfr4[4];
  if (w3) {
#pragma unroll
    for (int s = 0; s < 4; ++s)
      bfr4[s] = *reinterpret_cast<const bf16x8*>(
          &wt[(size_t)(256 + lr) * 128 + s * 32 + lg * 8]);
  }

#pragma unroll
  for (int t2 = 0; t2 < 2; ++t2) {
    int tile = blockIdx.x * 2 + t2;
    if (tile >= ntiles) break;
    if (t2) __syncthreads();
    gemm_tile_body<unsigned short>(X, bfr, bfr4, bl, bc, ylin_pk, xsb,
                                   asd_s, asd_d, n, tile * 32, xa,
                                   tid, wave, lane, lr, lg, f0, w3);
  }
}

// ---------------- final GEMM: out[N,64] = h@W_out + b (2 tiles/block) --------
__global__ __launch_bounds__(256, 3) void k_gemm_out(
    const unsigned short* __restrict__ X, const unsigned short* __restrict__ wot,
    const float* __restrict__ bias, float* __restrict__ out, int n, int ntiles) {
  __shared__ __align__(16) unsigned short xa[32][136];
  const int tid = threadIdx.x;
  const int wave = tid >> 6, lane = tid & 63;
  const int lr = lane & 15, lg = lane >> 4;

  bf16x8 bo[4];
#pragma unroll
  for (int s = 0; s < 4; ++s)
    bo[s] = *reinterpret_cast<const bf16x8*>(
        &wot[(size_t)(wave * 16 + lr) * 128 + s * 32 + lg * 8]);
  float bv = bias[wave * 16 + lr];

#pragma unroll
  for (int t2 = 0; t2 < 2; ++t2) {
    int tile = blockIdx.x * 2 + t2;
    if (tile >= ntiles) break;
    if (t2) __syncthreads();
    const int row0 = tile * 32;
#pragma unroll
    for (int i = 0; i < 2; ++i) {
      int c = tid + i * 256;
      int r = c >> 4, ko = c & 15;
      uint4 v = {0u, 0u, 0u, 0u};
      if (row0 + r < n)
        v = reinterpret_cast<const uint4*>(X)[(size_t)(row0 + r) * 16 + ko];
      *reinterpret_cast<uint4*>(&xa[r][ko * 8]) = v;
    }
    __syncthreads();

    f32x4 acc[2];
    acc[0] = (f32x4){0.f, 0.f, 0.f, 0.f};
    acc[1] = (f32x4){0.f, 0.f, 0.f, 0.f};
#pragma unroll
    for (int s = 0; s < 4; ++s) {
      bf16x8 a0 = *reinterpret_cast<const bf16x8*>(&xa[lr][s * 32 + lg * 8]);
      bf16x8 a1 = *reinterpret_cast<const bf16x8*>(&xa[16 + lr][s * 32 + lg * 8]);
      acc[0] = __builtin_amdgcn_mfma_f32_16x16x32_bf16(a0, bo[s], acc[0], 0, 0, 0);
      acc[1] = __builtin_amdgcn_mfma_f32_16x16x32_bf16(a1, bo[s], acc[1], 0, 0, 0);
    }
#pragma unroll
    for (int g = 0; g < 2; ++g)
#pragma unroll
      for (int r = 0; r < 4; ++r) {
        int row = row0 + g * 16 + lg * 4 + r;
        if (row < n) out[(size_t)row * 64 + wave * 16 + lr] = acc[g][r] + bv;
      }
  }
}

// ---------------- fused segment softmax + aggregation + node update ----------
// One wave per dst node. 16-edge software-pipelined chunks; branchless padding.
__global__ __launch_bounds__(256) void k_aggregate(
    const unsigned int* __restrict__ ylin_pk, const unsigned int* __restrict__ xsp,
    const unsigned short* __restrict__ asd_s, const unsigned short* __restrict__ asd_d,
    const int* __restrict__ rowptr, const unsigned short* __restrict__ col,
    unsigned int* __restrict__ hout_pk, int n) {
  int node = (blockIdx.x * blockDim.x + threadIdx.x) >> 6;
  if (node >= n) return;
  const int lane = threadIdx.x & 63;
  const int el = lane >> 3;
  const int hh = lane & 7;
  const int hb4 = (lane >> 3) << 2;
  const int beg = rowptr[node], end = rowptr[node + 1];

  const float ad_hh = bf2f(asd_d[(size_t)node * 8 + hh]);
  unsigned int y = __builtin_nontemporal_load(&ylin_pk[(size_t)node * 64 + lane]);

  float dsum = 0.f, acc0 = 0.f, acc1 = 0.f;
  int ebase = beg;
  for (; ebase + 8 < end; ebase += 16) {
    int eA = ebase + el;
    int eB = ebase + 8 + el;
    bool vB = eB < end;
    int esB = vB ? eB : (end - 1);
    int srcA = (int)col[eA];          // col reused across layers -> keep cached
    int srcB = (int)col[esB];
    float svA = bf2f(asd_s[(size_t)srcA * 8 + hh]) + ad_hh;
    float svB = bf2f(asd_s[(size_t)srcB * 8 + hh]) + ad_hh;
    svA = fmaxf(svA, NEG_SLOPE * svA);
    svB = fmaxf(svB, NEG_SLOPE * svB);
    float peA = __expf(svA);
    float peB = vB ? __expf(svB) : 0.f;
#pragma unroll
    for (int q = 0; q < 8; ++q) {
      float pq = __uint_as_float(__builtin_amdgcn_ds_bpermute(
          q * 32 + hb4, __float_as_uint(peA)));
      int sq = __builtin_amdgcn_readlane(srcA, q * 8);
      unsigned int xv = xsp[(size_t)sq * 64 + lane];
      dsum += pq;
      acc0 += pq * pklo(xv);
      acc1 += pq * pkhi(xv);
    }
#pragma unroll
    for (int q = 0; q < 8; ++q) {
      float pq = __uint_as_float(__builtin_amdgcn_ds_bpermute(
          q * 32 + hb4, __float_as_uint(peB)));
      int sq = __builtin_amdgcn_readlane(srcB, q * 8);
      unsigned int xv = xsp[(size_t)sq * 64 + lane];
      dsum += pq;
      acc0 += pq * pklo(xv);
      acc1 += pq * pkhi(xv);
    }
  }
  for (; ebase < end; ebase += 8) {
    int e1 = ebase + el;
    bool valid = e1 < end;
    int esafe = valid ? e1 : (end - 1);
    int srcp = (int)col[esafe];
    float sv = bf2f(asd_s[(size_t)srcp * 8 + hh]) + ad_hh;
    sv = fmaxf(sv, NEG_SLOPE * sv);
    float pe = valid ? __expf(sv) : 0.f;
#pragma unroll
    for (int q = 0; q < 8; ++q) {
      float pq = __uint_as_float(__builtin_amdgcn_ds_bpermute(
          q * 32 + hb4, __float_as_uint(pe)));
      int sq = __builtin_amdgcn_readlane(srcp, q * 8);
      unsigned int xv = xsp[(size_t)sq * 64 + lane];
      dsum += pq;
      acc0 += pq * pklo(xv);
      acc1 += pq * pkhi(xv);
    }
  }
  float inv = 1.f / (dsum + 1e-16f);
  float l0 = pklo(y) + acc0 * inv;
  float l1 = pkhi(y) + acc1 * inv;
  l0 = l0 > 0.f ? l0 : __expf(l0) - 1.f;
  l1 = l1 > 0.f ? l1 : __expf(l1) - 1.f;
  hout_pk[(size_t)node * 64 + lane] =
      (unsigned int)f2bf(l0) | ((unsigned int)f2bf(l1) << 16);
}

// ---------------- launch ----------------
extern "C" void kernel_launch(void* const* d_in, const int* in_sizes, int n_in,
                              void* d_out, int out_size, void* d_ws, size_t ws_size,
                              hipStream_t stream) {
  const float* x      = (const float*)d_in[0];
  const int*   ei     = (const int*)d_in[1];
  const float* W_lin0 = (const float*)d_in[2];
  const float* b_lin0 = (const float*)d_in[3];
  const float* W_src0 = (const float*)d_in[4];
  const float* W_dst0 = (const float*)d_in[5];
  const float* att_s0 = (const float*)d_in[6];
  const float* att_d0 = (const float*)d_in[7];
  const float* b_cnv0 = (const float*)d_in[8];
  const float* W_lin1 = (const float*)d_in[9];
  const float* b_lin1 = (const float*)d_in[10];
  const float* W_src1 = (const float*)d_in[11];
  const float* W_dst1 = (const float*)d_in[12];
  const float* att_s1 = (const float*)d_in[13];
  const float* att_d1 = (const float*)d_in[14];
  const float* b_cnv1 = (const float*)d_in[15];
  const float* W_out  = (const float*)d_in[16];
  const float* b_out  = (const float*)d_in[17];
  float* out = (float*)d_out;

  const int N = in_sizes[0] / 128;
  const int E = in_sizes[1] / 2;
  const int NB = (N + 1023) / 1024;
  const int MB32 = (N + 31) / 32;
  const int MBH = (MB32 + 1) / 2;      // 2 tiles per GEMM block
  const int SB4 = (E + 1023) / 1024;
  const int PACKB = (2 * 272 * 128 + 64 * 128 + 255) / 256;

  char* p = (char*)d_ws;
  unsigned int* ylin    = (unsigned int*)p;   p += (size_t)N * 64 * 4;
  unsigned short* xsb   = (unsigned short*)p; p += (size_t)N * 128 * 2;
  unsigned short* hb    = (unsigned short*)p; p += (size_t)N * 128 * 2;
  unsigned short* asd_s = (unsigned short*)p; p += (size_t)N * 8 * 2;
  unsigned short* asd_d = (unsigned short*)p; p += (size_t)N * 8 * 2;
  unsigned short* wt0   = (unsigned short*)p; p += (size_t)272 * 128 * 2;
  unsigned short* wt1   = (unsigned short*)p; p += (size_t)272 * 128 * 2;
  unsigned short* wot   = (unsigned short*)p; p += (size_t)64 * 128 * 2;
  int* rowptr = (int*)p;                      p += (size_t)(N + 4) * 4;
  int* deg    = (int*)p;                      p += (size_t)N * 4;
  int* lex    = (int*)p;                      p += (size_t)N * 4;
  int* bsum   = (int*)p;                      p += (size_t)256 * 4;
  unsigned short* col  = (unsigned short*)p;  p += (size_t)E * 2;
  unsigned short* rank = (unsigned short*)p;  p += (size_t)E * 2;

  dim3 b256(256);

  (void)hipMemsetAsync(deg, 0, (size_t)N * 4, stream);
  k_init<<<PACKB + SB4, b256, 0, stream>>>(
      W_lin0, W_src0, W_dst0, att_s0, att_d0,
      W_lin1, W_src1, W_dst1, att_s1, att_d1,
      W_out, wt0, wt1, wot, ei, deg, rank, E, PACKB);
  k_scan_local<<<NB, b256, 0, stream>>>(deg, lex, bsum, N);
  k_scan_add<<<(N + 256) / 256, b256, 0, stream>>>(lex, bsum, rowptr, N, NB, E);

  // layer-0 GEMM (2 tiles/block) ∪ atomic-free CSR scatter, interleaved
  k_gemm0_scatter<<<MBH + SB4, b256, 0, stream>>>(
      x, wt0, b_lin0, b_cnv0, ylin, xsb, asd_s, asd_d, N, MB32, MBH,
      ei, rowptr, rank, col, E, MBH + SB4);

  k_aggregate<<<(N + 3) / 4, b256, 0, stream>>>(
      ylin, (const unsigned int*)xsb, asd_s, asd_d, rowptr, col,
      (unsigned int*)hb, N);
  k_gemm_fused1<<<MBH, b256, 0, stream>>>(hb, wt1, b_lin1, b_cnv1,
                                          ylin, xsb, asd_s, asd_d, N, MB32);
  k_aggregate<<<(N + 3) / 4, b256, 0, stream>>>(
      ylin, (const unsigned int*)xsb, asd_s, asd_d, rowptr, col,
      (unsigned int*)hb, N);
  k_gemm_out<<<MBH, b256, 0, stream>>>(hb, wot, b_out, out, N, MB32);
}